// Round 7
// baseline (345.218 us; speedup 1.0000x reference)
//
#include <hip/hip_runtime.h>
#include <hip/hip_bf16.h>
#include <math.h>

typedef __attribute__((ext_vector_type(8))) short short8;
typedef __attribute__((ext_vector_type(4))) float floatx4;
typedef __attribute__((ext_vector_type(2))) float f32x2;

#define ATT_SCALE 0.865617024533378f  /* 0.6 * log2(e) */
#define C_ABS 0.6666666666667f        /* 0.4 / 0.6 */
#define PCLAMP 86.5f                  /* ~60 nats in log2 domain */

__device__ __forceinline__ float bf2f(unsigned short u) {
  union { unsigned int i; float f; } v; v.i = ((unsigned int)u) << 16; return v.f;
}
__device__ __forceinline__ unsigned short f2bf(float f) {
  union { float f; unsigned int u; } v; v.f = f;
  unsigned int r = (v.u + 0x7fffu + ((v.u >> 16) & 1u)) >> 16;
  return (unsigned short)r;
}
__device__ __forceinline__ int imin(int a, int b) { return a < b ? a : b; }
__device__ __forceinline__ int iclamp(int v, int lo, int hi) {
  return v < lo ? lo : (v > hi ? hi : v);
}
__device__ __forceinline__ float uasf(unsigned int u) {
  union { unsigned int i; float f; } v; v.i = u; return v.f;
}
__device__ __forceinline__ float exp2fast(float x) {
#if __has_builtin(__builtin_amdgcn_exp2f)
  return __builtin_amdgcn_exp2f(x);
#else
  return exp2f(x);
#endif
}
// elementwise |v| for f32x2 (pk_max(v,-v) when the builtin exists)
__device__ __forceinline__ f32x2 absv2(f32x2 v) {
#if __has_builtin(__builtin_elementwise_max)
  return __builtin_elementwise_max(v, -v);
#else
  f32x2 r; r[0] = fabsf(v[0]); r[1] = fabsf(v[1]); return r;
#endif
}
// 16-lane ring-rotation sum via DPP (pure VALU)
__device__ __forceinline__ float sum16(float x) {
  union { float f; int i; } a, t;
  a.f = x;
  t.i = __builtin_amdgcn_update_dpp(0, a.i, 0x121, 0xF, 0xF, true); a.f += t.f;
  t.i = __builtin_amdgcn_update_dpp(0, a.i, 0x122, 0xF, 0xF, true); a.f += t.f;
  t.i = __builtin_amdgcn_update_dpp(0, a.i, 0x124, 0xF, 0xF, true); a.f += t.f;
  t.i = __builtin_amdgcn_update_dpp(0, a.i, 0x128, 0xF, 0xF, true); a.f += t.f;
  return a.f;
}

// ---------------- sentinel: ws too small ----------------
__global__ void k_sentinel(float* out, float val) {
  if (threadIdx.x < 64) out[threadIdx.x] = val;
}

// ---------------- small-vector conversion segments ----------------
struct CvtSegs {
  const void* src[10];
  unsigned short* dst[10];
  int len[10];
};

// ---- mega prep: per-block dtype probe, then cvt8 | cvt_small | trans | hist --
__global__ void k_prep(const void* __restrict__ x, unsigned short* __restrict__ x_c,
                       int n8, CvtSegs segs,
                       const void* __restrict__ s0, const void* __restrict__ s1,
                       const void* __restrict__ s2, const void* __restrict__ s3,
                       unsigned short* __restrict__ d0, unsigned short* __restrict__ d1,
                       unsigned short* __restrict__ d2, unsigned short* __restrict__ d3,
                       const int* __restrict__ edst, int* deg, int E, int N,
                       int* dflag, int* colx, int ET,
                       float* __restrict__ att1s, float* __restrict__ att2s,
                       int nCvt8, int nTransB) {
  __shared__ int csh;
  if (threadIdx.x == 0) csh = 0;
  __syncthreads();
  {
    unsigned short u = ((const unsigned short*)x)[threadIdx.x];
    int e = (u >> 7) & 0xFF;
    atomicAdd(&csh, (u == 0) || (e >= 100 && e <= 145));
  }
  __syncthreads();
  int isf = (csh < 240);

  int b = blockIdx.x;
  if (b < nCvt8) {
    if (!isf) return;                       // bf16 input: x used directly
    int i = b * 256 + threadIdx.x;
    if (i >= n8) return;
    const float* s = (const float*)x + (size_t)i * 8;
    ushort4 a, c;
    a.x = f2bf(s[0]); a.y = f2bf(s[1]); a.z = f2bf(s[2]); a.w = f2bf(s[3]);
    c.x = f2bf(s[4]); c.y = f2bf(s[5]); c.z = f2bf(s[6]); c.w = f2bf(s[7]);
    ((ushort4*)x_c)[i * 2] = a;
    ((ushort4*)x_c)[i * 2 + 1] = c;
    return;
  }
  b -= nCvt8;
  if (b < 10) {
    if (b == 0) {
      if (threadIdx.x == 0) dflag[0] = isf;
      if (threadIdx.x >= 240) colx[ET + (threadIdx.x - 240)] = 0;  // 16-entry pad
    }
    int i = threadIdx.x;
    if (i < segs.len[b]) {
      float v = isf ? ((const float*)segs.src[b])[i]
                    : bf2f(((const unsigned short*)segs.src[b])[i]);
      segs.dst[b][i] = f2bf(v);
      // scaled f32 attention coefficients (exp2-domain scores)
      if (b == 2) att1s[i] = v * ATT_SCALE;
      if (b == 6) att2s[i] = v * ATT_SCALE;
    }
    return;
  }
  b -= 10;
  if (b < nTransB) {
    int idx = b * 256 + threadIdx.x;  // flat over 98304 elements
    const void* src; unsigned short* dst; int R, C, loc;
    if (idx < 32768)      { src = s0; dst = d0; R = 128; C = 256; loc = idx; }
    else if (idx < 65536) { src = s1; dst = d1; R = 128; C = 256; loc = idx - 32768; }
    else if (idx < 81920) { src = s2; dst = d2; R = 256; C = 64;  loc = idx - 65536; }
    else                  { src = s3; dst = d3; R = 256; C = 64;  loc = idx - 81920; }
    unsigned short u = isf ? f2bf(((const float*)src)[loc])
                           : ((const unsigned short*)src)[loc];
    int r = loc / C, cc = loc - r * C;
    dst[cc * R + r] = u;
    return;
  }
  b -= nTransB;
  // histogram: 4 edges per thread (independent atomic chains) [R8-measured]
  int base = b * 1024 + threadIdx.x;
#pragma unroll
  for (int k = 0; k < 4; ++k) {
    int e = base + k * 256;
    if (e < E) atomicAdd(&deg[iclamp(edst[e], 0, N - 1)], 1);
  }
}

// ---------------- scan stage 1: per-1024 block sums (deg+1 self-loop) -------
__global__ __launch_bounds__(1024) void k_scan1(const int* __restrict__ deg, int* bsum, int N) {
  __shared__ int sm[1024];
  int tid = threadIdx.x;
  int i = blockIdx.x * 1024 + tid;
  sm[tid] = (i < N) ? deg[i] + 1 : 0;
  __syncthreads();
  for (int off = 512; off > 0; off >>= 1) {
    if (tid < off) sm[tid] += sm[tid + off];
    __syncthreads();
  }
  if (tid == 0) bsum[blockIdx.x] = sm[0];
}

// ---- scan stage 2: Hillis-Steele + inline bsum prefix -> rowptr & cursor ----
__global__ __launch_bounds__(1024) void k_scan3(const int* __restrict__ deg,
                                                const int* __restrict__ bsum,
                                                int* rowptr, int* cursor, int N) {
  __shared__ int sm[1024];
  __shared__ int boff;
  int tid = threadIdx.x;
  if (tid == 0) {
    int r = 0;
    for (int b = 0; b < blockIdx.x; ++b) r += bsum[b];
    boff = r;
  }
  int i = blockIdx.x * 1024 + tid;
  int v = (i < N) ? deg[i] + 1 : 0;
  sm[tid] = v;
  __syncthreads();
  for (int off = 1; off < 1024; off <<= 1) {
    int t = (tid >= off) ? sm[tid - off] : 0;
    __syncthreads();
    sm[tid] += t;
    __syncthreads();
  }
  if (i < N) {
    int ex = sm[tid] - v + boff;
    rowptr[i] = ex;
    cursor[i] = ex;
    if (i == N - 1) rowptr[N] = ex + v;
  }
}

// ------ dual GEMM body, register-resident B + row loop (PF=1) ------
template <int K, int CT, int RT>
__device__ __forceinline__ void gemm2r_body(
    int bx, int by, int tid,
    const unsigned short* __restrict__ A,
    const unsigned short* __restrict__ BTl, const unsigned short* __restrict__ BTr,
    const unsigned short* __restrict__ bl, const unsigned short* __restrict__ br,
    unsigned short* __restrict__ outl, unsigned short* __restrict__ outr,
    int Nrows, int M) {
  constexpr int KI = K / 32;
  int lane = tid & 63;
  int wave = tid >> 6;
  int r = lane & 15, q = lane >> 4;
  int col0 = by * (4 * CT * 16) + wave * (CT * 16);
  int row0 = bx * (16 * RT);
  short8 Bl[KI][CT], Br[KI][CT];
#pragma unroll
  for (int t = 0; t < CT; ++t) {
    const unsigned short* bpl = BTl + (size_t)(col0 + t * 16 + r) * K + q * 8;
    const unsigned short* bpr = BTr + (size_t)(col0 + t * 16 + r) * K + q * 8;
#pragma unroll
    for (int k = 0; k < KI; ++k) {
      Bl[k][t] = *reinterpret_cast<const short8*>(bpl + k * 32);
      Br[k][t] = *reinterpret_cast<const short8*>(bpr + k * 32);
    }
  }
  float bvl[CT], bvr[CT];
#pragma unroll
  for (int t = 0; t < CT; ++t) {
    bvl[t] = bf2f(bl[col0 + t * 16 + r]);
    bvr[t] = bf2f(br[col0 + t * 16 + r]);
  }
  short8 a[KI], an[KI];
  {
    int ar0 = imin(row0 + r, Nrows - 1);
    const unsigned short* Ap = A + (size_t)ar0 * K + q * 8;
#pragma unroll
    for (int k = 0; k < KI; ++k) a[k] = *reinterpret_cast<const short8*>(Ap + k * 32);
  }
  for (int rt = 0; rt < RT; ++rt) {
    if (rt + 1 < RT) {
      int arn = imin(row0 + (rt + 1) * 16 + r, Nrows - 1);
      const unsigned short* Apn = A + (size_t)arn * K + q * 8;
#pragma unroll
      for (int k = 0; k < KI; ++k) an[k] = *reinterpret_cast<const short8*>(Apn + k * 32);
    }
    floatx4 accl[CT], accr[CT];
#pragma unroll
    for (int t = 0; t < CT; ++t) {
      accl[t] = (floatx4){0.f, 0.f, 0.f, 0.f};
      accr[t] = (floatx4){0.f, 0.f, 0.f, 0.f};
    }
#pragma unroll
    for (int k = 0; k < KI; ++k) {
#pragma unroll
      for (int t = 0; t < CT; ++t) {
        accl[t] = __builtin_amdgcn_mfma_f32_16x16x32_bf16(a[k], Bl[k][t], accl[t], 0, 0, 0);
        accr[t] = __builtin_amdgcn_mfma_f32_16x16x32_bf16(a[k], Br[k][t], accr[t], 0, 0, 0);
      }
    }
#pragma unroll
    for (int t = 0; t < CT; ++t) {
      int col = col0 + t * 16 + r;
#pragma unroll
      for (int rr = 0; rr < 4; ++rr) {
        int row = row0 + rt * 16 + q * 4 + rr;
        if (row < Nrows) {
          outl[(size_t)row * M + col] = f2bf(accl[t][rr] + bvl[t]);
          outr[(size_t)row * M + col] = f2bf(accr[t][rr] + bvr[t]);
        }
      }
    }
#pragma unroll
    for (int k = 0; k < KI; ++k) a[k] = an[k];
  }
}

// ------ phase1: INTERLEAVED layer-1 GEMM || scatter (role by block parity) ----
__global__ __launch_bounds__(256) void k_phase1(
    const unsigned short* __restrict__ A0, const unsigned short* __restrict__ A1,
    const int* __restrict__ dflag,
    const unsigned short* __restrict__ BTl, const unsigned short* __restrict__ BTr,
    const unsigned short* __restrict__ bl, const unsigned short* __restrict__ br,
    unsigned short* __restrict__ outl, unsigned short* __restrict__ outr,
    int Nrows, int M, int nG, int nS,
    const int* __restrict__ esrc, const int* __restrict__ edst,
    const int* __restrict__ rowptr, int* cursor, int* colx, int E, int N) {
  int b = blockIdx.x;
  int m2 = 2 * imin(nG, nS);
  bool isG;
  int idx;
  if (b < m2) { isG = (b & 1) == 0; idx = b >> 1; }
  else        { isG = nG > nS;      idx = imin(nG, nS) + (b - m2); }
  if (isG) {
    const unsigned short* A = dflag[0] ? A1 : A0;
    gemm2r_body<128, 2, 8>(idx >> 1, idx & 1, threadIdx.x, A, BTl, BTr, bl, br,
                           outl, outr, Nrows, M);
    return;
  }
  // scatter: 4 edges per thread (independent atomic chains)
  int ET = E + N;
  int base = idx * 1024 + threadIdx.x;
#pragma unroll
  for (int k = 0; k < 4; ++k) {
    int e = base + k * 256;
    if (e < ET) {
      if (e < E) {
        int s = iclamp(esrc[e], 0, N - 1), d = iclamp(edst[e], 0, N - 1);
        int pos = atomicAdd(&cursor[d], 1);
        colx[iclamp(pos, 0, ET - 1)] = s;
      } else {
        int i = e - E;                 // self-loop: fixed last slot, no atomic
        colx[rowptr[i + 1] - 1] = i;
      }
    }
  }
}

// ---------------- layer-2 GEMM ----------------
__global__ __launch_bounds__(256) void k_gemm2r_l2(
    const unsigned short* __restrict__ A,
    const unsigned short* __restrict__ BTl, const unsigned short* __restrict__ BTr,
    const unsigned short* __restrict__ bl, const unsigned short* __restrict__ br,
    unsigned short* __restrict__ outl, unsigned short* __restrict__ outr,
    int Nrows, int M) {
  gemm2r_body<256, 1, 4>(blockIdx.x, 0, threadIdx.x, A, BTl, BTr, bl, br,
                         outl, outr, Nrows, M);
}

// Packed-f32 per-edge score (R6-proven): q = pk_fma(a,v,ad);
// p = sum(q + c*|q|) via pk_max + pk_fma + pk_add.
#define EDGE_P(U, V01, V23, P)                                                \
  V01 = (f32x2){uasf(U.x << 16), uasf(U.x & 0xffff0000u)};                    \
  V23 = (f32x2){uasf(U.y << 16), uasf(U.y & 0xffff0000u)};                    \
  {                                                                           \
    f32x2 q01 = a01 * V01 + ad01;                                             \
    f32x2 q23 = a23 * V23 + ad23;                                             \
    f32x2 t01 = c01 * absv2(q01) + q01;                                       \
    f32x2 t23 = c23 * absv2(q23) + q23;                                       \
    f32x2 sv = t01 + t23;                                                     \
    P = sv[0] + sv[1];                                                        \
  }

#define EDGE_ACC(W, V01, V23)                                                 \
  {                                                                           \
    f32x2 wv = {W, W};                                                        \
    o01 = wv * V01 + o01;                                                     \
    o23 = wv * V23 + o23;                                                     \
  }

// Per-row edge loop. Entered with chunk0 gathers (ua..ud) and chunk1 indices
// (q0..q3) ALREADY issued by the caller (cross-row prologue pipelining).
// All colx reads and gathers are UNGUARDED: colx has a 16-entry zero pad and
// reads past `end` land on valid node indices whose slots the -INF mask kills
// (their w = exp2(-INF) = 0 contributes nothing).
template <int LOG_ROWB>
__device__ __forceinline__ void agg_row(
    const char* __restrict__ xsb, const int* __restrict__ colx, unsigned off2,
    int beg, int end,
    f32x2 a01, f32x2 a23, f32x2 c01, f32x2 c23, f32x2 ad01, f32x2 ad23,
    uint2 ua, uint2 ub, uint2 uc, uint2 ud,
    int q0, int q1, int q2, int q3,
    float& l, f32x2& o01, f32x2& o23) {
#define GATH(p) (*(const uint2*)(xsb + (((unsigned)(p) << LOG_ROWB) + off2)))
  for (int e = beg; e < end; e += 4) {
    uint2 na = GATH(q0), nb = GATH(q1), nc = GATH(q2), nd = GATH(q3);
    q0 = colx[e + 8]; q1 = colx[e + 9]; q2 = colx[e + 10]; q3 = colx[e + 11];
    f32x2 va01, va23, vb01, vb23, vc01, vc23, vd01, vd23;
    float pa, pb, pc, pd;
    EDGE_P(ua, va01, va23, pa)
    EDGE_P(ub, vb01, vb23, pb)
    EDGE_P(uc, vc01, vc23, pc)
    EDGE_P(ud, vd01, vd23, pd)
    pa = sum16(pa); pb = sum16(pb); pc = sum16(pc); pd = sum16(pd);
    pa = fminf(pa, PCLAMP);
    pb = (e + 1 < end) ? fminf(pb, PCLAMP) : -INFINITY;
    pc = (e + 2 < end) ? fminf(pc, PCLAMP) : -INFINITY;
    pd = (e + 3 < end) ? fminf(pd, PCLAMP) : -INFINITY;
    float wa = exp2fast(pa), wb = exp2fast(pb);
    float wc = exp2fast(pc), wd = exp2fast(pd);
    l += (wa + wb) + (wc + wd);
    EDGE_ACC(wa, va01, va23)
    EDGE_ACC(wb, vb01, vb23)
    EDGE_ACC(wc, vc01, vc23)
    EDGE_ACC(wd, vd01, vd23)
    ua = na; ub = nb; uc = nc; ud = nd;
  }
#undef GATH
}

// ------- layer-1 aggregation: H=4, C=64, TWO dsts per wave -------------------
// dst1's full front-end (colx chunk0 idx, chunk0 gathers, chunk1 idx) is
// issued BEFORE dst0's edge loop, so its ~800-cycle prologue chain hides
// under dst0's compute. rowptr triple read once (CSR contiguity: beg1 = end0).
__global__ __launch_bounds__(256) void k_agg_h4(
    const int* __restrict__ rowptr, const int* __restrict__ colx,
    const unsigned short* __restrict__ xs, const unsigned short* __restrict__ xd,
    const float* __restrict__ atts, const unsigned short* __restrict__ bias,
    unsigned short* __restrict__ hout, int N) {
  int lane = threadIdx.x & 63;
  int wid = (blockIdx.x * 256 + threadIdx.x) >> 6;
  int d0 = wid * 2;
  if (d0 >= N) return;
  int d1 = d0 + 1;
  bool v1 = d1 < N;
  int off = lane << 2;
  unsigned int off2 = (unsigned int)off * 2;
  const char* xsb = (const char*)xs;
  int beg0 = __builtin_amdgcn_readfirstlane(rowptr[d0]);
  int end0 = __builtin_amdgcn_readfirstlane(rowptr[d0 + 1]);
  int end1 = v1 ? __builtin_amdgcn_readfirstlane(rowptr[d1 + 1]) : end0;
  int beg1 = end0;
#define GATH4(p) (*(const uint2*)(xsb + (((unsigned)(p) << 9) + off2)))
  // dst0 front-end
  int p0 = colx[beg0], p1 = colx[beg0 + 1], p2 = colx[beg0 + 2], p3 = colx[beg0 + 3];
  uint2 uA0 = GATH4(p0), uA1 = GATH4(p1), uA2 = GATH4(p2), uA3 = GATH4(p3);
  int qa0 = colx[beg0 + 4], qa1 = colx[beg0 + 5], qa2 = colx[beg0 + 6], qa3 = colx[beg0 + 7];
  // dst1 front-end (in flight across dst0's whole loop)
  int r0 = colx[beg1], r1 = colx[beg1 + 1], r2 = colx[beg1 + 2], r3 = colx[beg1 + 3];
  uint2 uB0 = GATH4(r0), uB1 = GATH4(r1), uB2 = GATH4(r2), uB3 = GATH4(r3);
  int qb0 = colx[beg1 + 4], qb1 = colx[beg1 + 5], qb2 = colx[beg1 + 6], qb3 = colx[beg1 + 7];
#undef GATH4
  floatx4 av = *reinterpret_cast<const floatx4*>(atts + off);
  f32x2 a01 = {av[0], av[1]}, a23 = {av[2], av[3]};
  f32x2 c01 = {copysignf(C_ABS, av[0]), copysignf(C_ABS, av[1])};
  f32x2 c23 = {copysignf(C_ABS, av[2]), copysignf(C_ABS, av[3])};
  ushort4 du0 = *reinterpret_cast<const ushort4*>(xd + (size_t)d0 * 256 + off);
  ushort4 du1 = *reinterpret_cast<const ushort4*>(xd + (size_t)(v1 ? d1 : d0) * 256 + off);
  ushort4 bu = *reinterpret_cast<const ushort4*>(bias + off);
  float b0f = bf2f(bu.x), b1f = bf2f(bu.y), b2f = bf2f(bu.z), b3f = bf2f(bu.w);
  // ---- dst0 ----
  {
    f32x2 dd01 = {bf2f(du0.x), bf2f(du0.y)}, dd23 = {bf2f(du0.z), bf2f(du0.w)};
    f32x2 ad01 = a01 * dd01, ad23 = a23 * dd23;
    float l = 0.f;
    f32x2 o01 = {0.f, 0.f}, o23 = {0.f, 0.f};
    agg_row<9>(xsb, colx, off2, beg0, end0, a01, a23, c01, c23, ad01, ad23,
               uA0, uA1, uA2, uA3, qa0, qa1, qa2, qa3, l, o01, o23);
    float rl = 1.0f / l;
    ushort4 res;
    res.x = f2bf(fmaxf(fmaf(o01[0], rl, b0f), 0.f));
    res.y = f2bf(fmaxf(fmaf(o01[1], rl, b1f), 0.f));
    res.z = f2bf(fmaxf(fmaf(o23[0], rl, b2f), 0.f));
    res.w = f2bf(fmaxf(fmaf(o23[1], rl, b3f), 0.f));
    *reinterpret_cast<ushort4*>(hout + (size_t)d0 * 256 + off) = res;
  }
  // ---- dst1 (front-end long since returned) ----
  if (v1) {
    f32x2 dd01 = {bf2f(du1.x), bf2f(du1.y)}, dd23 = {bf2f(du1.z), bf2f(du1.w)};
    f32x2 ad01 = a01 * dd01, ad23 = a23 * dd23;
    float l = 0.f;
    f32x2 o01 = {0.f, 0.f}, o23 = {0.f, 0.f};
    agg_row<9>(xsb, colx, off2, beg1, end1, a01, a23, c01, c23, ad01, ad23,
               uB0, uB1, uB2, uB3, qb0, qb1, qb2, qb3, l, o01, o23);
    float rl = 1.0f / l;
    ushort4 res;
    res.x = f2bf(fmaxf(fmaf(o01[0], rl, b0f), 0.f));
    res.y = f2bf(fmaxf(fmaf(o01[1], rl, b1f), 0.f));
    res.z = f2bf(fmaxf(fmaf(o23[0], rl, b2f), 0.f));
    res.w = f2bf(fmaxf(fmaf(o23[1], rl, b3f), 0.f));
    *reinterpret_cast<ushort4*>(hout + (size_t)d1 * 256 + off) = res;
  }
}

// ------- layer-2 aggregation: H=1, C=64, EIGHT dsts per wave (2 quads) ------
// Each 16-lane group handles dst wid*8+g then wid*8+4+g; the second quad's
// front-end issues before the first quad's loop (same prologue hiding).
__global__ __launch_bounds__(256) void k_agg_h1(
    const int* __restrict__ rowptr, const int* __restrict__ colx,
    const unsigned short* __restrict__ xs, const unsigned short* __restrict__ xd,
    const float* __restrict__ atts, const unsigned short* __restrict__ bias,
    float* __restrict__ hout, int N) {
  int lane = threadIdx.x & 63;
  int wid = (blockIdx.x * 256 + threadIdx.x) >> 6;
  int g = lane >> 4, sl = lane & 15;
  int d0 = wid * 8 + g;
  int d1 = d0 + 4;
  bool v0 = d0 < N, v1 = d1 < N;
  int ds0 = v0 ? d0 : 0, ds1 = v1 ? d1 : 0;
  int cb = sl << 2;
  unsigned int cb2 = (unsigned int)cb * 2;
  const char* xsb = (const char*)xs;
  int beg0 = v0 ? rowptr[d0] : 0;
  int end0 = v0 ? rowptr[d0 + 1] : 0;
  int beg1 = v1 ? rowptr[d1] : 0;
  int end1 = v1 ? rowptr[d1 + 1] : 0;
#define GATH1(p) (*(const uint2*)(xsb + (((unsigned)(p) << 7) + cb2)))
  int p0 = colx[beg0], p1 = colx[beg0 + 1], p2 = colx[beg0 + 2], p3 = colx[beg0 + 3];
  uint2 uA0 = GATH1(p0), uA1 = GATH1(p1), uA2 = GATH1(p2), uA3 = GATH1(p3);
  int qa0 = colx[beg0 + 4], qa1 = colx[beg0 + 5], qa2 = colx[beg0 + 6], qa3 = colx[beg0 + 7];
  int r0 = colx[beg1], r1 = colx[beg1 + 1], r2 = colx[beg1 + 2], r3 = colx[beg1 + 3];
  uint2 uB0 = GATH1(r0), uB1 = GATH1(r1), uB2 = GATH1(r2), uB3 = GATH1(r3);
  int qb0 = colx[beg1 + 4], qb1 = colx[beg1 + 5], qb2 = colx[beg1 + 6], qb3 = colx[beg1 + 7];
#undef GATH1
  floatx4 av = *reinterpret_cast<const floatx4*>(atts + cb);
  f32x2 a01 = {av[0], av[1]}, a23 = {av[2], av[3]};
  f32x2 c01 = {copysignf(C_ABS, av[0]), copysignf(C_ABS, av[1])};
  f32x2 c23 = {copysignf(C_ABS, av[2]), copysignf(C_ABS, av[3])};
  ushort4 du0 = *reinterpret_cast<const ushort4*>(xd + (size_t)ds0 * 64 + cb);
  ushort4 du1 = *reinterpret_cast<const ushort4*>(xd + (size_t)ds1 * 64 + cb);
  ushort4 bu = *reinterpret_cast<const ushort4*>(bias + cb);
  float b0f = bf2f(bu.x), b1f = bf2f(bu.y), b2f = bf2f(bu.z), b3f = bf2f(bu.w);
  // ---- quad 0 ----
  {
    f32x2 dd01 = {bf2f(du0.x), bf2f(du0.y)}, dd23 = {bf2f(du0.z), bf2f(du0.w)};
    f32x2 ad01 = a01 * dd01, ad23 = a23 * dd23;
    float l = 0.f;
    f32x2 o01 = {0.f, 0.f}, o23 = {0.f, 0.f};
    agg_row<7>(xsb, colx, cb2, beg0, end0, a01, a23, c01, c23, ad01, ad23,
               uA0, uA1, uA2, uA3, qa0, qa1, qa2, qa3, l, o01, o23);
    if (v0) {
      float rl = 1.0f / l;
      floatx4 res;
      res[0] = fmaf(o01[0], rl, b0f);
      res[1] = fmaf(o01[1], rl, b1f);
      res[2] = fmaf(o23[0], rl, b2f);
      res[3] = fmaf(o23[1], rl, b3f);
      *reinterpret_cast<floatx4*>(hout + (size_t)d0 * 64 + cb) = res;
    }
  }
  // ---- quad 1 ----
  {
    f32x2 dd01 = {bf2f(du1.x), bf2f(du1.y)}, dd23 = {bf2f(du1.z), bf2f(du1.w)};
    f32x2 ad01 = a01 * dd01, ad23 = a23 * dd23;
    float l = 0.f;
    f32x2 o01 = {0.f, 0.f}, o23 = {0.f, 0.f};
    agg_row<7>(xsb, colx, cb2, beg1, end1, a01, a23, c01, c23, ad01, ad23,
               uB0, uB1, uB2, uB3, qb0, qb1, qb2, qb3, l, o01, o23);
    if (v1) {
      float rl = 1.0f / l;
      floatx4 res;
      res[0] = fmaf(o01[0], rl, b0f);
      res[1] = fmaf(o01[1], rl, b1f);
      res[2] = fmaf(o23[0], rl, b2f);
      res[3] = fmaf(o23[1], rl, b3f);
      *reinterpret_cast<floatx4*>(hout + (size_t)d1 * 64 + cb) = res;
    }
  }
}

// ---------------- mean pool over sorted batch [R8-measured] ----------------
__global__ __launch_bounds__(256) void k_pool(const float* __restrict__ h2,
                                              const int* __restrict__ batch,
                                              float* pool, int* cnt, int N) {
  int lane = threadIdx.x & 63;
  int wid = (blockIdx.x * 256 + threadIdx.x) >> 6;
  int n0 = wid * 32;
  if (n0 >= N) return;
  int nend = imin(n0 + 32, N);
  float acc = 0.f;
  int c = 0;
  int gcur = iclamp(batch[n0], 0, 63);
  for (int n = n0; n < nend; ++n) {
    int gg = iclamp(batch[n], 0, 63);
    if (gg != gcur) {
      atomicAdd(&pool[gcur * 64 + lane], acc);
      if (lane == 0) atomicAdd(&cnt[gcur], c);
      acc = 0.f; c = 0; gcur = gg;
    }
    acc += h2[(size_t)n * 64 + lane];
    c++;
  }
  atomicAdd(&pool[gcur * 64 + lane], acc);
  if (lane == 0) atomicAdd(&cnt[gcur], c);
}

// ---------------- final ----------------
__global__ void k_final(const float* __restrict__ pool, const int* __restrict__ cnt,
                        const unsigned short* __restrict__ Wlinc,
                        const unsigned short* __restrict__ blinc,
                        float* __restrict__ out) {
  int g = threadIdx.x;
  if (g >= 64) return;
  float inv = 1.f / fmaxf((float)cnt[g], 1.f);
  float s = 0.f;
  for (int c = 0; c < 64; ++c) s += pool[g * 64 + c] * bf2f(Wlinc[c]);
  out[g] = fmaf(s, inv, bf2f(blinc[0]));
}

extern "C" void kernel_launch(void* const* d_in, const int* in_sizes, int n_in,
                              void* d_out, int out_size, void* d_ws, size_t ws_size,
                              hipStream_t stream) {
  const void* x     = d_in[0];
  const int*  ei    = (const int*)d_in[1];
  const int*  batch = (const int*)d_in[2];
  const void* Wl1 = d_in[3];  const void* bl1 = d_in[4];
  const void* Wr1 = d_in[5];  const void* br1 = d_in[6];
  const void* att1 = d_in[7]; const void* bias1 = d_in[8];
  const void* Wl2 = d_in[9];  const void* bl2 = d_in[10];
  const void* Wr2 = d_in[11]; const void* br2 = d_in[12];
  const void* att2 = d_in[13]; const void* bias2 = d_in[14];
  const void* Wlin = d_in[15]; const void* blin = d_in[16];
  float* out = (float*)d_out;

  const int F = 128, HC = 256, C2 = 64;
  int N = in_sizes[0] / F;
  int E = in_sizes[1] / 2;
  int ET = E + N;
  const int* esrc = ei;
  const int* edst = ei + E;

  // ---- workspace carve-up ----
  char* w = (char*)d_ws;
  auto alloc = [&](size_t bytes) {
    char* p = w;
    w += (bytes + 255) & ~(size_t)255;
    return p;
  };
  int* dflag  = (int*)alloc(4);
  int* rowptr = (int*)alloc((size_t)(N + 1) * 4);
  int* cursor = (int*)alloc((size_t)N * 4);
  int* bsum   = (int*)alloc(1024 * 4);
  int* colx   = (int*)alloc((size_t)(ET + 16) * 4);
  unsigned short* smallc = (unsigned short*)alloc(4096);
  float* att1s = (float*)alloc(256 * 4);
  float* att2s = (float*)alloc(64 * 4);
  unsigned short* Wl1T = (unsigned short*)alloc((size_t)F * HC * 2);
  unsigned short* Wr1T = (unsigned short*)alloc((size_t)F * HC * 2);
  unsigned short* Wl2T = (unsigned short*)alloc((size_t)HC * C2 * 2);
  unsigned short* Wr2T = (unsigned short*)alloc((size_t)HC * C2 * 2);
  int* deg    = (int*)alloc((size_t)N * 4);     // zero-region start
  float* pool = (float*)alloc(64 * 64 * 4);
  int* cnt    = (int*)alloc(64 * 4);            // zero-region end
  unsigned short* xs1  = (unsigned short*)alloc((size_t)N * HC * 2);
  unsigned short* xd1  = (unsigned short*)alloc((size_t)N * HC * 2);
  unsigned short* h1   = (unsigned short*)alloc((size_t)N * HC * 2);
  size_t required = (size_t)(w - (char*)d_ws);
  size_t zlen = (size_t)((char*)cnt + 256 - (char*)deg);

  unsigned short* x_c = h1;
  unsigned short* xs2 = xs1;
  unsigned short* xd2 = xs1 + (size_t)N * C2;
  float*          h2  = (float*)xd1;

  unsigned short* bl1c   = smallc + 0;
  unsigned short* br1c   = smallc + 256;
  unsigned short* att1c  = smallc + 512;
  unsigned short* bias1c = smallc + 768;
  unsigned short* bl2c   = smallc + 1024;
  unsigned short* br2c   = smallc + 1088;
  unsigned short* att2c  = smallc + 1152;
  unsigned short* bias2c = smallc + 1216;
  unsigned short* Wlinc  = smallc + 1280;
  unsigned short* blinc  = smallc + 1344;

  if (ws_size < required) {
    k_sentinel<<<1, 64, 0, stream>>>(out, 1000.f + (float)(ws_size >> 20));
    return;
  }

  hipMemsetAsync(deg, 0, zlen, stream);

  // ---- mega prep: probe | cvt8 | small cvts | transposes | hist(4/thread) ----
  CvtSegs segs;
  const void* ssrc[10] = {bl1, br1, att1, bias1, bl2, br2, att2, bias2, Wlin, blin};
  unsigned short* sdst[10] = {bl1c, br1c, att1c, bias1c, bl2c, br2c, att2c, bias2c, Wlinc, blinc};
  int slen[10] = {256, 256, 256, 256, 64, 64, 64, 64, 64, 1};
  for (int i = 0; i < 10; ++i) { segs.src[i] = ssrc[i]; segs.dst[i] = sdst[i]; segs.len[i] = slen[i]; }
  int n8 = N * F / 8;
  int nCvt8 = (n8 + 255) / 256;
  int nTransB = (2 * F * HC + 2 * HC * C2 + 255) / 256;
  int nHist = (E + 1023) / 1024;
  k_prep<<<nCvt8 + 10 + nTransB + nHist, 256, 0, stream>>>(
      x, x_c, n8, segs, Wl1, Wr1, Wl2, Wr2, Wl1T, Wr1T, Wl2T, Wr2T,
      edst, deg, E, N, dflag, colx, ET, att1s, att2s, nCvt8, nTransB);

  // ---- scan ----
  int nb = (N + 1023) / 1024;
  k_scan1<<<nb, 1024, 0, stream>>>(deg, bsum, N);
  k_scan3<<<nb, 1024, 0, stream>>>(deg, bsum, rowptr, cursor, N);

  // ---- phase1: interleaved layer-1 GEMM || scatter ----
  int nG = ((N + 127) / 128) * 2;
  int nS = (ET + 1023) / 1024;
  k_phase1<<<nG + nS, 256, 0, stream>>>(
      (const unsigned short*)x, x_c, dflag, Wl1T, Wr1T, bl1c, br1c, xs1, xd1,
      N, HC, nG, nS, esrc, edst, rowptr, cursor, colx, E, N);

  // ---- layer 1 aggregation: 2 dsts/wave, cross-dst prologue pipelining ----
  int nw4 = (N + 1) / 2;
  k_agg_h4<<<(nw4 + 3) / 4, 256, 0, stream>>>(rowptr, colx, xs1, xd1, att1s, bias1c, h1, N);

  // ---- layer 2 ----
  k_gemm2r_l2<<<(N + 63) / 64, 256, 0, stream>>>(h1, Wl2T, Wr2T, bl2c, br2c, xs2, xd2, N, C2);
  int nw1 = (N + 7) / 8;
  k_agg_h1<<<(nw1 + 3) / 4, 256, 0, stream>>>(rowptr, colx, xs2, xd2, att2s, bias2c, h2, N);

  // ---- pool + final ----
  int pw = (N + 31) / 32;
  k_pool<<<(pw + 3) / 4, 256, 0, stream>>>(h2, batch, pool, cnt, N);
  k_final<<<1, 64, 0, stream>>>(pool, cnt, Wlinc, blinc, out);
}

// Round 8
// 335.914 us; speedup vs baseline: 1.0277x; 1.0277x over previous
//
#include <hip/hip_runtime.h>
#include <hip/hip_bf16.h>
#include <math.h>

typedef __attribute__((ext_vector_type(8))) short short8;
typedef __attribute__((ext_vector_type(4))) float floatx4;
typedef __attribute__((ext_vector_type(2))) float f32x2;

#define ATT_SCALE 0.865617024533378f  /* 0.6 * log2(e) */
#define C_ABS 0.6666666666667f        /* 0.4 / 0.6 */
#define PCLAMP 86.5f                  /* ~60 nats in log2 domain */

__device__ __forceinline__ float bf2f(unsigned short u) {
  union { unsigned int i; float f; } v; v.i = ((unsigned int)u) << 16; return v.f;
}
__device__ __forceinline__ unsigned short f2bf(float f) {
  union { float f; unsigned int u; } v; v.f = f;
  unsigned int r = (v.u + 0x7fffu + ((v.u >> 16) & 1u)) >> 16;
  return (unsigned short)r;
}
__device__ __forceinline__ int imin(int a, int b) { return a < b ? a : b; }
__device__ __forceinline__ int iclamp(int v, int lo, int hi) {
  return v < lo ? lo : (v > hi ? hi : v);
}
__device__ __forceinline__ float uasf(unsigned int u) {
  union { unsigned int i; float f; } v; v.i = u; return v.f;
}
__device__ __forceinline__ float exp2fast(float x) {
#if __has_builtin(__builtin_amdgcn_exp2f)
  return __builtin_amdgcn_exp2f(x);
#else
  return exp2f(x);
#endif
}
// elementwise |v| for f32x2 (pk_max(v,-v) when the builtin exists)
__device__ __forceinline__ f32x2 absv2(f32x2 v) {
#if __has_builtin(__builtin_elementwise_max)
  return __builtin_elementwise_max(v, -v);
#else
  f32x2 r; r[0] = fabsf(v[0]); r[1] = fabsf(v[1]); return r;
#endif
}
// 16-lane ring-rotation sum via DPP (pure VALU)
__device__ __forceinline__ float sum16(float x) {
  union { float f; int i; } a, t;
  a.f = x;
  t.i = __builtin_amdgcn_update_dpp(0, a.i, 0x121, 0xF, 0xF, true); a.f += t.f;
  t.i = __builtin_amdgcn_update_dpp(0, a.i, 0x122, 0xF, 0xF, true); a.f += t.f;
  t.i = __builtin_amdgcn_update_dpp(0, a.i, 0x124, 0xF, 0xF, true); a.f += t.f;
  t.i = __builtin_amdgcn_update_dpp(0, a.i, 0x128, 0xF, 0xF, true); a.f += t.f;
  return a.f;
}

// ---------------- sentinel: ws too small ----------------
__global__ void k_sentinel(float* out, float val) {
  if (threadIdx.x < 64) out[threadIdx.x] = val;
}

// ---------------- small-vector conversion segments ----------------
struct CvtSegs {
  const void* src[10];
  unsigned short* dst[10];
  int len[10];
};

// ---- mega prep: per-block dtype probe, then cvt8 | cvt_small | trans | hist --
__global__ void k_prep(const void* __restrict__ x, unsigned short* __restrict__ x_c,
                       int n8, CvtSegs segs,
                       const void* __restrict__ s0, const void* __restrict__ s1,
                       const void* __restrict__ s2, const void* __restrict__ s3,
                       unsigned short* __restrict__ d0, unsigned short* __restrict__ d1,
                       unsigned short* __restrict__ d2, unsigned short* __restrict__ d3,
                       const int* __restrict__ edst, int* deg, int E, int N,
                       int* dflag, int* colx, int ET,
                       float* __restrict__ att1s, float* __restrict__ att2s,
                       int nCvt8, int nTransB) {
  __shared__ int csh;
  if (threadIdx.x == 0) csh = 0;
  __syncthreads();
  {
    unsigned short u = ((const unsigned short*)x)[threadIdx.x];
    int e = (u >> 7) & 0xFF;
    atomicAdd(&csh, (u == 0) || (e >= 100 && e <= 145));
  }
  __syncthreads();
  int isf = (csh < 240);

  int b = blockIdx.x;
  if (b < nCvt8) {
    if (!isf) return;                       // bf16 input: x used directly
    int i = b * 256 + threadIdx.x;
    if (i >= n8) return;
    const float* s = (const float*)x + (size_t)i * 8;
    ushort4 a, c;
    a.x = f2bf(s[0]); a.y = f2bf(s[1]); a.z = f2bf(s[2]); a.w = f2bf(s[3]);
    c.x = f2bf(s[4]); c.y = f2bf(s[5]); c.z = f2bf(s[6]); c.w = f2bf(s[7]);
    ((ushort4*)x_c)[i * 2] = a;
    ((ushort4*)x_c)[i * 2 + 1] = c;
    return;
  }
  b -= nCvt8;
  if (b < 10) {
    if (b == 0) {
      if (threadIdx.x == 0) dflag[0] = isf;
      if (threadIdx.x >= 240) colx[ET + (threadIdx.x - 240)] = 0;  // 16-entry pad
    }
    int i = threadIdx.x;
    if (i < segs.len[b]) {
      float v = isf ? ((const float*)segs.src[b])[i]
                    : bf2f(((const unsigned short*)segs.src[b])[i]);
      segs.dst[b][i] = f2bf(v);
      // scaled f32 attention coefficients (exp2-domain scores)
      if (b == 2) att1s[i] = v * ATT_SCALE;
      if (b == 6) att2s[i] = v * ATT_SCALE;
    }
    return;
  }
  b -= 10;
  if (b < nTransB) {
    int idx = b * 256 + threadIdx.x;  // flat over 98304 elements
    const void* src; unsigned short* dst; int R, C, loc;
    if (idx < 32768)      { src = s0; dst = d0; R = 128; C = 256; loc = idx; }
    else if (idx < 65536) { src = s1; dst = d1; R = 128; C = 256; loc = idx - 32768; }
    else if (idx < 81920) { src = s2; dst = d2; R = 256; C = 64;  loc = idx - 65536; }
    else                  { src = s3; dst = d3; R = 256; C = 64;  loc = idx - 81920; }
    unsigned short u = isf ? f2bf(((const float*)src)[loc])
                           : ((const unsigned short*)src)[loc];
    int r = loc / C, cc = loc - r * C;
    dst[cc * R + r] = u;
    return;
  }
  b -= nTransB;
  // histogram: 4 edges per thread (independent atomic chains) [R8-measured]
  int base = b * 1024 + threadIdx.x;
#pragma unroll
  for (int k = 0; k < 4; ++k) {
    int e = base + k * 256;
    if (e < E) atomicAdd(&deg[iclamp(edst[e], 0, N - 1)], 1);
  }
}

// ---------------- scan stage 1: per-1024 block sums (deg+1 self-loop) -------
__global__ __launch_bounds__(1024) void k_scan1(const int* __restrict__ deg, int* bsum, int N) {
  __shared__ int sm[1024];
  int tid = threadIdx.x;
  int i = blockIdx.x * 1024 + tid;
  sm[tid] = (i < N) ? deg[i] + 1 : 0;
  __syncthreads();
  for (int off = 512; off > 0; off >>= 1) {
    if (tid < off) sm[tid] += sm[tid + off];
    __syncthreads();
  }
  if (tid == 0) bsum[blockIdx.x] = sm[0];
}

// ---- scan stage 2: Hillis-Steele + inline bsum prefix -> rowptr & cursor ----
__global__ __launch_bounds__(1024) void k_scan3(const int* __restrict__ deg,
                                                const int* __restrict__ bsum,
                                                int* rowptr, int* cursor, int N) {
  __shared__ int sm[1024];
  __shared__ int boff;
  int tid = threadIdx.x;
  if (tid == 0) {
    int r = 0;
    for (int b = 0; b < blockIdx.x; ++b) r += bsum[b];
    boff = r;
  }
  int i = blockIdx.x * 1024 + tid;
  int v = (i < N) ? deg[i] + 1 : 0;
  sm[tid] = v;
  __syncthreads();
  for (int off = 1; off < 1024; off <<= 1) {
    int t = (tid >= off) ? sm[tid - off] : 0;
    __syncthreads();
    sm[tid] += t;
    __syncthreads();
  }
  if (i < N) {
    int ex = sm[tid] - v + boff;
    rowptr[i] = ex;
    cursor[i] = ex;
    if (i == N - 1) rowptr[N] = ex + v;
  }
}

// ------ dual GEMM body, register-resident B + row loop (PF=1) ------
template <int K, int CT, int RT>
__device__ __forceinline__ void gemm2r_body(
    int bx, int by, int tid,
    const unsigned short* __restrict__ A,
    const unsigned short* __restrict__ BTl, const unsigned short* __restrict__ BTr,
    const unsigned short* __restrict__ bl, const unsigned short* __restrict__ br,
    unsigned short* __restrict__ outl, unsigned short* __restrict__ outr,
    int Nrows, int M) {
  constexpr int KI = K / 32;
  int lane = tid & 63;
  int wave = tid >> 6;
  int r = lane & 15, q = lane >> 4;
  int col0 = by * (4 * CT * 16) + wave * (CT * 16);
  int row0 = bx * (16 * RT);
  short8 Bl[KI][CT], Br[KI][CT];
#pragma unroll
  for (int t = 0; t < CT; ++t) {
    const unsigned short* bpl = BTl + (size_t)(col0 + t * 16 + r) * K + q * 8;
    const unsigned short* bpr = BTr + (size_t)(col0 + t * 16 + r) * K + q * 8;
#pragma unroll
    for (int k = 0; k < KI; ++k) {
      Bl[k][t] = *reinterpret_cast<const short8*>(bpl + k * 32);
      Br[k][t] = *reinterpret_cast<const short8*>(bpr + k * 32);
    }
  }
  float bvl[CT], bvr[CT];
#pragma unroll
  for (int t = 0; t < CT; ++t) {
    bvl[t] = bf2f(bl[col0 + t * 16 + r]);
    bvr[t] = bf2f(br[col0 + t * 16 + r]);
  }
  short8 a[KI], an[KI];
  {
    int ar0 = imin(row0 + r, Nrows - 1);
    const unsigned short* Ap = A + (size_t)ar0 * K + q * 8;
#pragma unroll
    for (int k = 0; k < KI; ++k) a[k] = *reinterpret_cast<const short8*>(Ap + k * 32);
  }
  for (int rt = 0; rt < RT; ++rt) {
    if (rt + 1 < RT) {
      int arn = imin(row0 + (rt + 1) * 16 + r, Nrows - 1);
      const unsigned short* Apn = A + (size_t)arn * K + q * 8;
#pragma unroll
      for (int k = 0; k < KI; ++k) an[k] = *reinterpret_cast<const short8*>(Apn + k * 32);
    }
    floatx4 accl[CT], accr[CT];
#pragma unroll
    for (int t = 0; t < CT; ++t) {
      accl[t] = (floatx4){0.f, 0.f, 0.f, 0.f};
      accr[t] = (floatx4){0.f, 0.f, 0.f, 0.f};
    }
#pragma unroll
    for (int k = 0; k < KI; ++k) {
#pragma unroll
      for (int t = 0; t < CT; ++t) {
        accl[t] = __builtin_amdgcn_mfma_f32_16x16x32_bf16(a[k], Bl[k][t], accl[t], 0, 0, 0);
        accr[t] = __builtin_amdgcn_mfma_f32_16x16x32_bf16(a[k], Br[k][t], accr[t], 0, 0, 0);
      }
    }
#pragma unroll
    for (int t = 0; t < CT; ++t) {
      int col = col0 + t * 16 + r;
#pragma unroll
      for (int rr = 0; rr < 4; ++rr) {
        int row = row0 + rt * 16 + q * 4 + rr;
        if (row < Nrows) {
          outl[(size_t)row * M + col] = f2bf(accl[t][rr] + bvl[t]);
          outr[(size_t)row * M + col] = f2bf(accr[t][rr] + bvr[t]);
        }
      }
    }
#pragma unroll
    for (int k = 0; k < KI; ++k) a[k] = an[k];
  }
}

// ------ phase1: INTERLEAVED layer-1 GEMM || scatter (role by block parity) ----
__global__ __launch_bounds__(256) void k_phase1(
    const unsigned short* __restrict__ A0, const unsigned short* __restrict__ A1,
    const int* __restrict__ dflag,
    const unsigned short* __restrict__ BTl, const unsigned short* __restrict__ BTr,
    const unsigned short* __restrict__ bl, const unsigned short* __restrict__ br,
    unsigned short* __restrict__ outl, unsigned short* __restrict__ outr,
    int Nrows, int M, int nG, int nS,
    const int* __restrict__ esrc, const int* __restrict__ edst,
    const int* __restrict__ rowptr, int* cursor, int* colx, int E, int N) {
  int b = blockIdx.x;
  int m2 = 2 * imin(nG, nS);
  bool isG;
  int idx;
  if (b < m2) { isG = (b & 1) == 0; idx = b >> 1; }
  else        { isG = nG > nS;      idx = imin(nG, nS) + (b - m2); }
  if (isG) {
    const unsigned short* A = dflag[0] ? A1 : A0;
    gemm2r_body<128, 2, 8>(idx >> 1, idx & 1, threadIdx.x, A, BTl, BTr, bl, br,
                           outl, outr, Nrows, M);
    return;
  }
  // scatter: 4 edges per thread (independent atomic chains)
  int ET = E + N;
  int base = idx * 1024 + threadIdx.x;
#pragma unroll
  for (int k = 0; k < 4; ++k) {
    int e = base + k * 256;
    if (e < ET) {
      if (e < E) {
        int s = iclamp(esrc[e], 0, N - 1), d = iclamp(edst[e], 0, N - 1);
        int pos = atomicAdd(&cursor[d], 1);
        colx[iclamp(pos, 0, ET - 1)] = s;
      } else {
        int i = e - E;                 // self-loop: fixed last slot, no atomic
        colx[rowptr[i + 1] - 1] = i;
      }
    }
  }
}

// ---------------- layer-2 GEMM ----------------
__global__ __launch_bounds__(256) void k_gemm2r_l2(
    const unsigned short* __restrict__ A,
    const unsigned short* __restrict__ BTl, const unsigned short* __restrict__ BTr,
    const unsigned short* __restrict__ bl, const unsigned short* __restrict__ br,
    unsigned short* __restrict__ outl, unsigned short* __restrict__ outr,
    int Nrows, int M) {
  gemm2r_body<256, 1, 4>(blockIdx.x, 0, threadIdx.x, A, BTl, BTr, bl, br,
                         outl, outr, Nrows, M);
}

// Packed-f32 per-edge score (R6-proven): q = pk_fma(a,v,ad);
// p = sum(q + c*|q|) via pk_max + pk_fma + pk_add.
#define EDGE_P(U, V01, V23, P)                                                \
  V01 = (f32x2){uasf(U.x << 16), uasf(U.x & 0xffff0000u)};                    \
  V23 = (f32x2){uasf(U.y << 16), uasf(U.y & 0xffff0000u)};                    \
  {                                                                           \
    f32x2 q01 = a01 * V01 + ad01;                                             \
    f32x2 q23 = a23 * V23 + ad23;                                             \
    f32x2 t01 = c01 * absv2(q01) + q01;                                       \
    f32x2 t23 = c23 * absv2(q23) + q23;                                       \
    f32x2 sv = t01 + t23;                                                     \
    P = sv[0] + sv[1];                                                        \
  }

#define EDGE_ACC(W, V01, V23)                                                 \
  {                                                                           \
    f32x2 wv = {W, W};                                                        \
    o01 = wv * V01 + o01;                                                     \
    o23 = wv * V23 + o23;                                                     \
  }

// 4-edge chunk: score + masked exp2 + accumulate (uses e/end/l/o from scope)
#define AGG_CHUNK(U0, U1, U2, U3)                                             \
  {                                                                           \
    f32x2 va01, va23, vb01, vb23, vc01, vc23, vd01, vd23;                     \
    float pa, pb, pc, pd;                                                     \
    EDGE_P(U0, va01, va23, pa)                                                \
    EDGE_P(U1, vb01, vb23, pb)                                                \
    EDGE_P(U2, vc01, vc23, pc)                                                \
    EDGE_P(U3, vd01, vd23, pd)                                                \
    pa = sum16(pa); pb = sum16(pb); pc = sum16(pc); pd = sum16(pd);           \
    pa = fminf(pa, PCLAMP);                                                   \
    pb = (e + 1 < end) ? fminf(pb, PCLAMP) : -INFINITY;                       \
    pc = (e + 2 < end) ? fminf(pc, PCLAMP) : -INFINITY;                       \
    pd = (e + 3 < end) ? fminf(pd, PCLAMP) : -INFINITY;                       \
    float wa = exp2fast(pa), wb = exp2fast(pb);                               \
    float wc = exp2fast(pc), wd = exp2fast(pd);                               \
    l += (wa + wb) + (wc + wd);                                               \
    EDGE_ACC(wa, va01, va23)                                                  \
    EDGE_ACC(wb, vb01, vb23)                                                  \
    EDGE_ACC(wc, vc01, vc23)                                                  \
    EDGE_ACC(wd, vd01, vd23)                                                  \
  }

// ------- layer-1 aggregation: H=4, C=64, one wave per dst --------------------
// 3-buffer DISTANCE-2 gather pipeline: per phase, issue gathers for chunk i+2
// (indices loaded one phase earlier), load indices for chunk i+3, compute
// chunk i. Gather->use distance ~2 phases of issue (~240cy) vs L2/L3 latency.
// All issues GUARDED (R7 lesson: unguarded overrun gathers cost +38MB FETCH).
// colx index loads are wave-uniform -> SGPR loads, no VALU. Natural dst order.
__global__ __launch_bounds__(256) void k_agg_h4(
    const int* __restrict__ rowptr, const int* __restrict__ colx,
    const unsigned short* __restrict__ xs, const unsigned short* __restrict__ xd,
    const float* __restrict__ atts, const unsigned short* __restrict__ bias,
    unsigned short* __restrict__ hout, int N) {
  int lane = threadIdx.x & 63;
  int dst = (blockIdx.x * 256 + threadIdx.x) >> 6;
  if (dst >= N) return;
  int off = lane << 2;
  unsigned int off2 = (unsigned int)off * 2;
  const char* xsb = (const char*)xs;
  int beg = __builtin_amdgcn_readfirstlane(rowptr[dst]);
  int end = __builtin_amdgcn_readfirstlane(rowptr[dst + 1]);
#define GATH(p) (*(const uint2*)(xsb + (((unsigned)(p) << 9) + off2)))
  // ---- pipeline prologue: chunk0 gathers, chunk1 gathers, chunk2 indices ----
  int pA0 = colx[beg], pA1 = colx[beg + 1], pA2 = colx[beg + 2], pA3 = colx[beg + 3];
  uint2 uA0 = GATH(pA0), uA1 = GATH(pA1), uA2 = GATH(pA2), uA3 = GATH(pA3);
  uint2 uB0 = {0, 0}, uB1 = {0, 0}, uB2 = {0, 0}, uB3 = {0, 0};
  uint2 uC0 = {0, 0}, uC1 = {0, 0}, uC2 = {0, 0}, uC3 = {0, 0};
  int pB0 = 0, pB1 = 0, pB2 = 0, pB3 = 0;
  int pC0 = 0, pC1 = 0, pC2 = 0, pC3 = 0;
  if (beg + 4 < end) {
    pB0 = colx[beg + 4]; pB1 = colx[beg + 5]; pB2 = colx[beg + 6]; pB3 = colx[beg + 7];
    uB0 = GATH(pB0); uB1 = GATH(pB1); uB2 = GATH(pB2); uB3 = GATH(pB3);
  }
  if (beg + 8 < end) {
    pC0 = colx[beg + 8]; pC1 = colx[beg + 9]; pC2 = colx[beg + 10]; pC3 = colx[beg + 11];
  }
  // per-dst setup overlaps prologue gather latency
  floatx4 av = *reinterpret_cast<const floatx4*>(atts + off);
  ushort4 du = *reinterpret_cast<const ushort4*>(xd + (size_t)dst * 256 + off);
  f32x2 a01 = {av[0], av[1]}, a23 = {av[2], av[3]};
  f32x2 dd01 = {bf2f(du.x), bf2f(du.y)}, dd23 = {bf2f(du.z), bf2f(du.w)};
  f32x2 ad01 = a01 * dd01, ad23 = a23 * dd23;
  f32x2 c01 = {copysignf(C_ABS, av[0]), copysignf(C_ABS, av[1])};
  f32x2 c23 = {copysignf(C_ABS, av[2]), copysignf(C_ABS, av[3])};
  float l = 0.f;
  f32x2 o01 = {0.f, 0.f}, o23 = {0.f, 0.f};
  // ---- 3-phase rotating loop (no buffer moves) ----
  for (int e = beg;;) {
    // phase A: compute uA(e); issue uC <- pC (chunk e+8); load pA <- e+12
    if (e + 8 < end) { uC0 = GATH(pC0); uC1 = GATH(pC1); uC2 = GATH(pC2); uC3 = GATH(pC3); }
    if (e + 12 < end) {
      pA0 = colx[e + 12]; pA1 = colx[e + 13]; pA2 = colx[e + 14]; pA3 = colx[e + 15];
    }
    AGG_CHUNK(uA0, uA1, uA2, uA3)
    e += 4; if (e >= end) break;
    // phase B: compute uB(e); issue uA <- pA (chunk e+8); load pB <- e+12
    if (e + 8 < end) { uA0 = GATH(pA0); uA1 = GATH(pA1); uA2 = GATH(pA2); uA3 = GATH(pA3); }
    if (e + 12 < end) {
      pB0 = colx[e + 12]; pB1 = colx[e + 13]; pB2 = colx[e + 14]; pB3 = colx[e + 15];
    }
    AGG_CHUNK(uB0, uB1, uB2, uB3)
    e += 4; if (e >= end) break;
    // phase C: compute uC(e); issue uB <- pB (chunk e+8); load pC <- e+12
    if (e + 8 < end) { uB0 = GATH(pB0); uB1 = GATH(pB1); uB2 = GATH(pB2); uB3 = GATH(pB3); }
    if (e + 12 < end) {
      pC0 = colx[e + 12]; pC1 = colx[e + 13]; pC2 = colx[e + 14]; pC3 = colx[e + 15];
    }
    AGG_CHUNK(uC0, uC1, uC2, uC3)
    e += 4; if (e >= end) break;
  }
#undef GATH
  float rl = 1.0f / l;
  ushort4 bu = *reinterpret_cast<const ushort4*>(bias + off);
  ushort4 res;
  res.x = f2bf(fmaxf(fmaf(o01[0], rl, bf2f(bu.x)), 0.f));
  res.y = f2bf(fmaxf(fmaf(o01[1], rl, bf2f(bu.y)), 0.f));
  res.z = f2bf(fmaxf(fmaf(o23[0], rl, bf2f(bu.z)), 0.f));
  res.w = f2bf(fmaxf(fmaf(o23[1], rl, bf2f(bu.w)), 0.f));
  *reinterpret_cast<ushort4*>(hout + (size_t)dst * 256 + off) = res;
}

// ------- layer-2 aggregation: H=1, C=64, 4 dst/wave, 4-edge unroll (R6) -----
__global__ __launch_bounds__(256) void k_agg_h1(
    const int* __restrict__ rowptr, const int* __restrict__ colx,
    const unsigned short* __restrict__ xs, const unsigned short* __restrict__ xd,
    const float* __restrict__ atts, const unsigned short* __restrict__ bias,
    float* __restrict__ hout, int N) {
  int lane = threadIdx.x & 63;
  int wid = (blockIdx.x * 256 + threadIdx.x) >> 6;
  int g = lane >> 4, sl = lane & 15;
  int dst = wid * 4 + g;
  bool valid = dst < N;
  int dsafe = valid ? dst : 0;
  int cb = sl << 2;
  unsigned int cb2 = (unsigned int)cb * 2;
  const char* xsb = (const char*)xs;
  floatx4 av = *reinterpret_cast<const floatx4*>(atts + cb);
  ushort4 du = *reinterpret_cast<const ushort4*>(xd + (size_t)dsafe * 64 + cb);
  f32x2 a01 = {av[0], av[1]}, a23 = {av[2], av[3]};
  f32x2 dd01 = {bf2f(du.x), bf2f(du.y)}, dd23 = {bf2f(du.z), bf2f(du.w)};
  f32x2 ad01 = a01 * dd01, ad23 = a23 * dd23;
  f32x2 c01 = {copysignf(C_ABS, av[0]), copysignf(C_ABS, av[1])};
  f32x2 c23 = {copysignf(C_ABS, av[2]), copysignf(C_ABS, av[3])};
  float l = 0.f;
  f32x2 o01 = {0.f, 0.f}, o23 = {0.f, 0.f};
  int beg = valid ? rowptr[dst] : 0;
  int end = valid ? rowptr[dst + 1] : 0;
  if (end > beg) {
    int p0 = colx[beg], p1 = colx[beg + 1], p2 = colx[beg + 2], p3 = colx[beg + 3];
    uint2 ua = *(const uint2*)(xsb + (((unsigned)p0 << 7) + cb2));
    uint2 ub = *(const uint2*)(xsb + (((unsigned)p1 << 7) + cb2));
    uint2 uc = *(const uint2*)(xsb + (((unsigned)p2 << 7) + cb2));
    uint2 ud = *(const uint2*)(xsb + (((unsigned)p3 << 7) + cb2));
    int q0 = 0, q1 = 0, q2 = 0, q3 = 0;
    if (beg + 4 < end) {
      q0 = colx[beg + 4]; q1 = colx[beg + 5]; q2 = colx[beg + 6]; q3 = colx[beg + 7];
    }
    for (int e = beg; e < end; e += 4) {
      uint2 na = ua, nb = ub, nc = uc, nd = ud;
      if (e + 4 < end) {
        na = *(const uint2*)(xsb + (((unsigned)q0 << 7) + cb2));
        nb = *(const uint2*)(xsb + (((unsigned)q1 << 7) + cb2));
        nc = *(const uint2*)(xsb + (((unsigned)q2 << 7) + cb2));
        nd = *(const uint2*)(xsb + (((unsigned)q3 << 7) + cb2));
      }
      if (e + 8 < end) {
        q0 = colx[e + 8]; q1 = colx[e + 9]; q2 = colx[e + 10]; q3 = colx[e + 11];
      }
      f32x2 va01, va23, vb01, vb23, vc01, vc23, vd01, vd23;
      float pa, pb, pc, pd;
      EDGE_P(ua, va01, va23, pa)
      EDGE_P(ub, vb01, vb23, pb)
      EDGE_P(uc, vc01, vc23, pc)
      EDGE_P(ud, vd01, vd23, pd)
      pa = sum16(pa); pb = sum16(pb); pc = sum16(pc); pd = sum16(pd);
      pa = fminf(pa, PCLAMP);
      pb = (e + 1 < end) ? fminf(pb, PCLAMP) : -INFINITY;
      pc = (e + 2 < end) ? fminf(pc, PCLAMP) : -INFINITY;
      pd = (e + 3 < end) ? fminf(pd, PCLAMP) : -INFINITY;
      float wa = exp2fast(pa), wb = exp2fast(pb);
      float wc = exp2fast(pc), wd = exp2fast(pd);
      l += (wa + wb) + (wc + wd);
      EDGE_ACC(wa, va01, va23)
      EDGE_ACC(wb, vb01, vb23)
      EDGE_ACC(wc, vc01, vc23)
      EDGE_ACC(wd, vd01, vd23)
      ua = na; ub = nb; uc = nc; ud = nd;
    }
  }
  if (valid) {
    float rl = 1.0f / l;
    ushort4 bu = *reinterpret_cast<const ushort4*>(bias + cb);
    floatx4 res;
    res[0] = fmaf(o01[0], rl, bf2f(bu.x));
    res[1] = fmaf(o01[1], rl, bf2f(bu.y));
    res[2] = fmaf(o23[0], rl, bf2f(bu.z));
    res[3] = fmaf(o23[1], rl, bf2f(bu.w));
    *reinterpret_cast<floatx4*>(hout + (size_t)dst * 64 + cb) = res;
  }
}

// ---------------- mean pool over sorted batch [R8-measured] ----------------
__global__ __launch_bounds__(256) void k_pool(const float* __restrict__ h2,
                                              const int* __restrict__ batch,
                                              float* pool, int* cnt, int N) {
  int lane = threadIdx.x & 63;
  int wid = (blockIdx.x * 256 + threadIdx.x) >> 6;
  int n0 = wid * 32;
  if (n0 >= N) return;
  int nend = imin(n0 + 32, N);
  float acc = 0.f;
  int c = 0;
  int gcur = iclamp(batch[n0], 0, 63);
  for (int n = n0; n < nend; ++n) {
    int gg = iclamp(batch[n], 0, 63);
    if (gg != gcur) {
      atomicAdd(&pool[gcur * 64 + lane], acc);
      if (lane == 0) atomicAdd(&cnt[gcur], c);
      acc = 0.f; c = 0; gcur = gg;
    }
    acc += h2[(size_t)n * 64 + lane];
    c++;
  }
  atomicAdd(&pool[gcur * 64 + lane], acc);
  if (lane == 0) atomicAdd(&cnt[gcur], c);
}

// ---------------- final ----------------
__global__ void k_final(const float* __restrict__ pool, const int* __restrict__ cnt,
                        const unsigned short* __restrict__ Wlinc,
                        const unsigned short* __restrict__ blinc,
                        float* __restrict__ out) {
  int g = threadIdx.x;
  if (g >= 64) return;
  float inv = 1.f / fmaxf((float)cnt[g], 1.f);
  float s = 0.f;
  for (int c = 0; c < 64; ++c) s += pool[g * 64 + c] * bf2f(Wlinc[c]);
  out[g] = fmaf(s, inv, bf2f(blinc[0]));
}

extern "C" void kernel_launch(void* const* d_in, const int* in_sizes, int n_in,
                              void* d_out, int out_size, void* d_ws, size_t ws_size,
                              hipStream_t stream) {
  const void* x     = d_in[0];
  const int*  ei    = (const int*)d_in[1];
  const int*  batch = (const int*)d_in[2];
  const void* Wl1 = d_in[3];  const void* bl1 = d_in[4];
  const void* Wr1 = d_in[5];  const void* br1 = d_in[6];
  const void* att1 = d_in[7]; const void* bias1 = d_in[8];
  const void* Wl2 = d_in[9];  const void* bl2 = d_in[10];
  const void* Wr2 = d_in[11]; const void* br2 = d_in[12];
  const void* att2 = d_in[13]; const void* bias2 = d_in[14];
  const void* Wlin = d_in[15]; const void* blin = d_in[16];
  float* out = (float*)d_out;

  const int F = 128, HC = 256, C2 = 64;
  int N = in_sizes[0] / F;
  int E = in_sizes[1] / 2;
  int ET = E + N;
  const int* esrc = ei;
  const int* edst = ei + E;

  // ---- workspace carve-up ----
  char* w = (char*)d_ws;
  auto alloc = [&](size_t bytes) {
    char* p = w;
    w += (bytes + 255) & ~(size_t)255;
    return p;
  };
  int* dflag  = (int*)alloc(4);
  int* rowptr = (int*)alloc((size_t)(N + 1) * 4);
  int* cursor = (int*)alloc((size_t)N * 4);
  int* bsum   = (int*)alloc(1024 * 4);
  int* colx   = (int*)alloc((size_t)(ET + 16) * 4);
  unsigned short* smallc = (unsigned short*)alloc(4096);
  float* att1s = (float*)alloc(256 * 4);
  float* att2s = (float*)alloc(64 * 4);
  unsigned short* Wl1T = (unsigned short*)alloc((size_t)F * HC * 2);
  unsigned short* Wr1T = (unsigned short*)alloc((size_t)F * HC * 2);
  unsigned short* Wl2T = (unsigned short*)alloc((size_t)HC * C2 * 2);
  unsigned short* Wr2T = (unsigned short*)alloc((size_t)HC * C2 * 2);
  int* deg    = (int*)alloc((size_t)N * 4);     // zero-region start
  float* pool = (float*)alloc(64 * 64 * 4);
  int* cnt    = (int*)alloc(64 * 4);            // zero-region end
  unsigned short* xs1  = (unsigned short*)alloc((size_t)N * HC * 2);
  unsigned short* xd1  = (unsigned short*)alloc((size_t)N * HC * 2);
  unsigned short* h1   = (unsigned short*)alloc((size_t)N * HC * 2);
  size_t required = (size_t)(w - (char*)d_ws);
  size_t zlen = (size_t)((char*)cnt + 256 - (char*)deg);

  unsigned short* x_c = h1;
  unsigned short* xs2 = xs1;
  unsigned short* xd2 = xs1 + (size_t)N * C2;
  float*          h2  = (float*)xd1;

  unsigned short* bl1c   = smallc + 0;
  unsigned short* br1c   = smallc + 256;
  unsigned short* att1c  = smallc + 512;
  unsigned short* bias1c = smallc + 768;
  unsigned short* bl2c   = smallc + 1024;
  unsigned short* br2c   = smallc + 1088;
  unsigned short* att2c  = smallc + 1152;
  unsigned short* bias2c = smallc + 1216;
  unsigned short* Wlinc  = smallc + 1280;
  unsigned short* blinc  = smallc + 1344;

  if (ws_size < required) {
    k_sentinel<<<1, 64, 0, stream>>>(out, 1000.f + (float)(ws_size >> 20));
    return;
  }

  hipMemsetAsync(deg, 0, zlen, stream);

  // ---- mega prep: probe | cvt8 | small cvts | transposes | hist(4/thread) ----
  CvtSegs segs;
  const void* ssrc[10] = {bl1, br1, att1, bias1, bl2, br2, att2, bias2, Wlin, blin};
  unsigned short* sdst[10] = {bl1c, br1c, att1c, bias1c, bl2c, br2c, att2c, bias2c, Wlinc, blinc};
  int slen[10] = {256, 256, 256, 256, 64, 64, 64, 64, 64, 1};
  for (int i = 0; i < 10; ++i) { segs.src[i] = ssrc[i]; segs.dst[i] = sdst[i]; segs.len[i] = slen[i]; }
  int n8 = N * F / 8;
  int nCvt8 = (n8 + 255) / 256;
  int nTransB = (2 * F * HC + 2 * HC * C2 + 255) / 256;
  int nHist = (E + 1023) / 1024;
  k_prep<<<nCvt8 + 10 + nTransB + nHist, 256, 0, stream>>>(
      x, x_c, n8, segs, Wl1, Wr1, Wl2, Wr2, Wl1T, Wr1T, Wl2T, Wr2T,
      edst, deg, E, N, dflag, colx, ET, att1s, att2s, nCvt8, nTransB);

  // ---- scan ----
  int nb = (N + 1023) / 1024;
  k_scan1<<<nb, 1024, 0, stream>>>(deg, bsum, N);
  k_scan3<<<nb, 1024, 0, stream>>>(deg, bsum, rowptr, cursor, N);

  // ---- phase1: interleaved layer-1 GEMM || scatter ----
  int nG = ((N + 127) / 128) * 2;
  int nS = (ET + 1023) / 1024;
  k_phase1<<<nG + nS, 256, 0, stream>>>(
      (const unsigned short*)x, x_c, dflag, Wl1T, Wr1T, bl1c, br1c, xs1, xd1,
      N, HC, nG, nS, esrc, edst, rowptr, cursor, colx, E, N);

  // ---- layer 1 aggregation: distance-2 gather pipeline ----
  k_agg_h4<<<(N + 3) / 4, 256, 0, stream>>>(rowptr, colx, xs1, xd1, att1s, bias1c, h1, N);

  // ---- layer 2 ----
  k_gemm2r_l2<<<(N + 63) / 64, 256, 0, stream>>>(h1, Wl2T, Wr2T, bl2c, br2c, xs2, xd2, N, C2);
  k_agg_h1<<<(N + 15) / 16, 256, 0, stream>>>(rowptr, colx, xs2, xd2, att2s, bias2c, h2, N);

  // ---- pool + final ----
  int pw = (N + 31) / 32;
  k_pool<<<(pw + 3) / 4, 256, 0, stream>>>(h2, batch, pool, cnt, N);
  k_final<<<1, 64, 0, stream>>>(pool, cnt, Wlinc, blinc, out);
}